// Round 7
// baseline (282.701 us; speedup 1.0000x reference)
//
#include <hip/hip_runtime.h>
#include <cfloat>
#include <cmath>

#define NB 2048
#define BB 16
#define DD 128
#define HH 64
#define MAXC 5
#define NT 1024

// ---- ws layout (float offsets) ----
#define OFF_P 0                                   // [BB*NB][HH]      8 MB
#define OFF_PARTIAL (OFF_P + BB * NB * HH)        // [BB][16][DD]     (prep->init)
#define OFF_LOGITS OFF_PARTIAL                    // [BB][NB]         (selA->selB, overlays partial)
#define OFF_QV (OFF_PARTIAL + BB * 16 * DD)       // [BB][HH]
#define OFF_HRUN (OFF_QV + BB * HH)               // [BB][HH]
#define OFF_GI (OFF_HRUN + BB * HH)               // [BB][MAXC][3*HH]
#define OFF_WIN (OFF_GI + BB * MAXC * 3 * HH)     // [BB][16] ints

// ---------------- Threefry-2x32 (JAX-exact) ----------------
__device__ __forceinline__ unsigned rotl32(unsigned v, int d) {
  return (v << d) | (v >> (32 - d));
}

__device__ __forceinline__ void tf2x32(unsigned k0, unsigned k1, unsigned x0, unsigned x1,
                                       unsigned& o0, unsigned& o1) {
  unsigned ks2 = k0 ^ k1 ^ 0x1BD11BDAu;
  x0 += k0; x1 += k1;
#define RND(r) { x0 += x1; x1 = rotl32(x1, r); x1 ^= x0; }
  RND(13) RND(15) RND(26) RND(6)   x0 += k1;  x1 += ks2 + 1u;
  RND(17) RND(29) RND(16) RND(24)  x0 += ks2; x1 += k0 + 2u;
  RND(13) RND(15) RND(26) RND(6)   x0 += k0;  x1 += k1 + 3u;
  RND(17) RND(29) RND(16) RND(24)  x0 += k1;  x1 += ks2 + 4u;
  RND(13) RND(15) RND(26) RND(6)   x0 += ks2; x1 += k0 + 5u;
#undef RND
  o0 = x0; o1 = x1;
}

__device__ __forceinline__ float gumbel_for(unsigned k0, unsigned k1, unsigned idx) {
  unsigned o0, o1;
  tf2x32(k0, k1, 0u, idx, o0, o1);
  unsigned bits = o0 ^ o1;
  float u = __uint_as_float((bits >> 9) | 0x3f800000u) - 1.0f;
  float uu = u + 1e-8f;
  return -logf(-logf(uu) + 1e-8f);
}

__device__ __forceinline__ unsigned long long packKey(float y, int n) {
  unsigned u = __float_as_uint(y);
  u = (u & 0x80000000u) ? ~u : (u | 0x80000000u);
  return ((unsigned long long)u << 32) | (unsigned)(~(unsigned)n);
}
__device__ __forceinline__ int decodeKey(unsigned long long k) {
  return k ? (int)(~(unsigned)k) : -1;
}

// ---------------- prep: P-GEMM tiles + mean partials ----------------
__global__ __launch_bounds__(NT) void gvp_prep(
    const float* __restrict__ x, const float* __restrict__ W1, float* __restrict__ ws) {
  __shared__ __align__(16) float s_W1[HH][DD + 4];
  __shared__ float sp[8][DD];
  const int bid = blockIdx.x, tid = threadIdx.x;
  float* P = ws + OFF_P;
  float* partial = ws + OFF_PARTIAL;

  if (bid < 128) {
    for (int i = tid; i < HH * (DD / 4); i += NT) {
      int r = i >> 5, q = i & 31;
      *(float4*)&s_W1[r][q * 4] = *(const float4*)(W1 + (size_t)r * (DD + HH) + q * 4);
    }
    __syncthreads();
    const int jg = tid & 15, ng = tid >> 4;
    const int j0 = jg * 4;
    const size_t n0 = (size_t)bid * 256 + ng * 4;
    const float4* x4 = (const float4*)x;
    float acc[4][4];
#pragma unroll
    for (int i = 0; i < 4; i++)
#pragma unroll
      for (int q = 0; q < 4; q++) acc[i][q] = 0.f;
    for (int kq = 0; kq < 32; kq++) {
      float4 xv[4], wv[4];
#pragma unroll
      for (int i = 0; i < 4; i++) xv[i] = x4[(n0 + i) * 32 + kq];
#pragma unroll
      for (int q = 0; q < 4; q++) wv[q] = *(const float4*)&s_W1[j0 + q][kq * 4];
#pragma unroll
      for (int i = 0; i < 4; i++)
#pragma unroll
        for (int q = 0; q < 4; q++)
          acc[i][q] += xv[i].x * wv[q].x + xv[i].y * wv[q].y +
                       xv[i].z * wv[q].z + xv[i].w * wv[q].w;
    }
#pragma unroll
    for (int i = 0; i < 4; i++)
#pragma unroll
      for (int q = 0; q < 4; q++)
        P[(n0 + i) * HH + j0 + q] = acc[i][q];
  } else {
    const int bm = bid - 128;
    const int b = bm >> 4, chunk = bm & 15;
    const int d = tid & (DD - 1), part = tid >> 7;
    float acc = 0.f;
    const int base = chunk * 128 + part;
#pragma unroll
    for (int k = 0; k < 16; k++)
      acc += x[((size_t)b * NB + base + k * 8) * DD + d];
    sp[part][d] = acc;
    __syncthreads();
    if (tid < DD) {
      float m = 0.f;
#pragma unroll
      for (int p = 0; p < 8; p++) m += sp[p][tid];
      partial[((size_t)b * 16 + chunk) * DD + tid] = m;
    }
  }
}

// ---------------- init: mean -> ctx -> q, h=0 ----------------
__global__ __launch_bounds__(256) void gvp_init(
    const float* __restrict__ Wc, const float* __restrict__ bc,
    const float* __restrict__ W1, const float* __restrict__ b1, float* __restrict__ ws) {
  __shared__ __align__(16) float s_mean[DD], s_ctx[HH];
  __shared__ __align__(16) float s_W1c[HH][HH + 4];
  const int b = blockIdx.x, tid = threadIdx.x;
  for (int i = tid; i < HH * 16; i += 256) {
    int r = i >> 4, q = i & 15;
    *(float4*)&s_W1c[r][q * 4] = *(const float4*)(W1 + (size_t)r * (DD + HH) + DD + q * 4);
  }
  if (tid < DD) {
    float m = 0.f;
#pragma unroll
    for (int k = 0; k < 16; k++) m += ws[OFF_PARTIAL + ((size_t)b * 16 + k) * DD + tid];
    s_mean[tid] = m * (1.0f / NB);
  }
  __syncthreads();
  {  // ctx = bc + Wc @ mean (4-lane split)
    int row = tid >> 2, g = tid & 3;
    const float4* wr = (const float4*)(Wc + (size_t)row * DD) + g * 8;
    const float4* m4 = (const float4*)s_mean + g * 8;
    float s = 0.f;
#pragma unroll
    for (int i = 0; i < 8; i++) {
      float4 w = wr[i], m = m4[i];
      s += w.x * m.x + w.y * m.y + w.z * m.z + w.w * m.w;
    }
    s += __shfl_xor(s, 1);
    s += __shfl_xor(s, 2);
    if (g == 0) s_ctx[row] = s + bc[row];
  }
  __syncthreads();
  {  // q = b1 + W1c @ ctx
    int row = tid >> 2, g = tid & 3;
    const float4* wr = (const float4*)&s_W1c[row][0] + g * 4;
    const float4* c4 = (const float4*)s_ctx + g * 4;
    float s = 0.f;
#pragma unroll
    for (int i = 0; i < 4; i++) {
      float4 w = wr[i], cc = c4[i];
      s += w.x * cc.x + w.y * cc.y + w.z * cc.z + w.w * cc.w;
    }
    s += __shfl_xor(s, 1);
    s += __shfl_xor(s, 2);
    if (g == 0) ws[OFF_QV + b * HH + row] = s + b1[row];
  }
  if (tid < HH) ws[OFF_HRUN + b * HH + tid] = 0.f;
}

// ---------------- selA: logits + sel0 ----------------
__global__ __launch_bounds__(NT) void gvp_selA(
    const int* __restrict__ mask, const float* __restrict__ W2, const float* __restrict__ b2,
    float* __restrict__ ws, int c) {
  __shared__ __align__(16) float s_q[HH], s_W2[HH];
  __shared__ int s_win[16];
  __shared__ unsigned long long s_key0;
  const int b = blockIdx.x, tid = threadIdx.x;
  const int n0 = tid, n1 = tid + NT;
  int* winners = (int*)(ws + OFF_WIN) + b * 16;

  if (tid == 0) s_key0 = 0ull;
  if (tid < HH) s_q[tid] = ws[OFF_QV + b * HH + tid];
  else if (tid < 2 * HH) s_W2[tid - HH] = W2[tid - HH];
  else if (tid < 2 * HH + 16) {
    int i = tid - 2 * HH;
    s_win[i] = (i < 3 * c) ? winners[i] : -1;
  }
  __syncthreads();

  // logits
  const float4* P4 = (const float4*)(ws + OFF_P) + (size_t)b * NB * 16;
  const float4* q4 = (const float4*)s_q;
  const float4* w4 = (const float4*)s_W2;
  const float4* p0 = P4 + (size_t)n0 * 16;
  const float4* p1 = P4 + (size_t)n1 * 16;
  float l0 = b2[0], l1 = l0;
#pragma unroll
  for (int i = 0; i < 16; i++) {
    float4 pa = p0[i], pb = p1[i], qv = q4[i], w = w4[i];
    l0 += w.x * fmaxf(pa.x + qv.x, 0.f) + w.y * fmaxf(pa.y + qv.y, 0.f) +
          w.z * fmaxf(pa.z + qv.z, 0.f) + w.w * fmaxf(pa.w + qv.w, 0.f);
    l1 += w.x * fmaxf(pb.x + qv.x, 0.f) + w.y * fmaxf(pb.y + qv.y, 0.f) +
          w.z * fmaxf(pb.z + qv.z, 0.f) + w.w * fmaxf(pb.w + qv.w, 0.f);
  }
  ws[OFF_LOGITS + (size_t)b * NB + n0] = l0;
  ws[OFF_LOGITS + (size_t)b * NB + n1] = l1;

  // on-the-fly gumbel for sel0
  unsigned k0, k1;
  tf2x32(0u, 42u, 0u, (unsigned)(2 * c), k0, k1);
  bool a0 = mask[b * NB + n0] != 0, a1 = mask[b * NB + n1] != 0;
  for (int i = 0; i < 3 * c; i++) {
    int w = s_win[i];
    a0 &= (n0 != w);
    a1 &= (n1 != w);
  }
  float bv = -FLT_MAX;
  int bi = NB;
  if (a0) { float y = l0 + gumbel_for(k0, k1, (unsigned)(b * NB + n0)); if (y > bv) { bv = y; bi = n0; } }
  if (a1) { float y = l1 + gumbel_for(k0, k1, (unsigned)(b * NB + n1)); if (y > bv) { bv = y; bi = n1; } }
#pragma unroll
  for (int off = 32; off; off >>= 1) {
    float ov = __shfl_down(bv, off);
    int oi = __shfl_down(bi, off);
    if (ov > bv || (ov == bv && oi < bi)) { bv = ov; bi = oi; }
  }
  if ((tid & 63) == 0 && bi < NB) atomicMax(&s_key0, packKey(bv, bi));
  __syncthreads();
  if (tid == 0) winners[3 * c] = decodeKey(s_key0);
}

// ---------------- selB: BFS + sel1 + sel2 + gi/emb ----------------
__global__ __launch_bounds__(NT) void gvp_selB(
    const float* __restrict__ x, const float* __restrict__ adj, const int* __restrict__ mask,
    const float* __restrict__ Wih, const float* __restrict__ bih,
    float* __restrict__ ws, float* __restrict__ out_feat, int c) {
  __shared__ __align__(16) float s_logits[NB];
  __shared__ unsigned char s_avail[NB], s_reach[NB];
  __shared__ short s_list[128];
  __shared__ int s_cnt;
  __shared__ unsigned long long s_key1;
  __shared__ unsigned long long s_top2[16][2];
  __shared__ int s_win[16];
  const int b = blockIdx.x, tid = threadIdx.x, wid = tid >> 6;
  const int n0 = tid, n1 = tid + NT;
  int* winners = (int*)(ws + OFF_WIN) + b * 16;
  const float4* adj4 = (const float4*)(adj + (size_t)b * NB * NB);
  const size_t xb = (size_t)b * NB * DD;

  // P0a: staging + zero init
  if (tid == 0) { s_cnt = 0; s_key1 = 0ull; }
  if (tid >= 32 && tid < 64) s_top2[(tid - 32) >> 1][(tid - 32) & 1] = 0ull;
  if (tid >= 64 && tid < 80) {
    int i = tid - 64;
    s_win[i] = (i <= 3 * c) ? winners[i] : -1;
  }
  s_logits[n0] = ws[OFF_LOGITS + (size_t)b * NB + n0];
  s_logits[n1] = ws[OFF_LOGITS + (size_t)b * NB + n1];
  s_avail[n0] = (mask[b * NB + n0] != 0) ? 1 : 0;
  s_avail[n1] = (mask[b * NB + n1] != 0) ? 1 : 0;
  __syncthreads();

  // P0b: H0 — seed row
  const int seed = s_win[3 * c];
  if (tid < 512) {
    if (seed >= 0) {
      float4 a = adj4[(size_t)seed * 512 + tid];
      int m = tid << 2;
      unsigned f0 = a.x > 0.f, f1 = a.y > 0.f, f2 = a.z > 0.f, f3 = a.w > 0.f;
      unsigned r = f0 | (f1 << 8) | (f2 << 16) | (f3 << 24);
      if ((seed >> 2) == tid) r |= 1u << ((seed & 3) * 8);
      ((unsigned*)s_reach)[tid] = r;
      if (f0 && m != seed)     { int p = atomicAdd(&s_cnt, 1); if (p < 128) s_list[p] = (short)m; }
      if (f1 && m + 1 != seed) { int p = atomicAdd(&s_cnt, 1); if (p < 128) s_list[p] = (short)(m + 1); }
      if (f2 && m + 2 != seed) { int p = atomicAdd(&s_cnt, 1); if (p < 128) s_list[p] = (short)(m + 2); }
      if (f3 && m + 3 != seed) { int p = atomicAdd(&s_cnt, 1); if (p < 128) s_list[p] = (short)(m + 3); }
    } else {
      ((unsigned*)s_reach)[tid] = 0u;
    }
  }
  // gumbel for sel1/sel2 (pure ALU, overlaps)
  unsigned k10, k11, k20, k21;
  tf2x32(0u, 42u, 0u, (unsigned)(2 * c + 1000), k10, k11);
  tf2x32(0u, 42u, 0u, (unsigned)(2 * c + 1001), k20, k21);
  float g1a = gumbel_for(k10, k11, (unsigned)(b * NB + n0));
  float g1b = gumbel_for(k10, k11, (unsigned)(b * NB + n1));
  float g2a = gumbel_for(k20, k21, (unsigned)(b * NB + n0));
  float g2b = gumbel_for(k20, k21, (unsigned)(b * NB + n1));
  __syncthreads();

  // P1: H1 — frontier rows
  if (seed >= 0) {
    int cnt = min(s_cnt, 128);
    int m4 = tid & 511, rg = tid >> 9;
    bool a0 = false, a1 = false, a2 = false, a3 = false;
#pragma unroll
    for (int k = 0; k < 20; k++) {
      int li = rg + 2 * k;
      if (li < cnt) {
        int n = s_list[li];
        float4 a = adj4[(size_t)n * 512 + m4];
        a0 |= a.x > 0.f; a1 |= a.y > 0.f; a2 |= a.z > 0.f; a3 |= a.w > 0.f;
      }
    }
    for (int li = rg + 40; li < cnt; li += 2) {
      int n = s_list[li];
      float4 a = adj4[(size_t)n * 512 + m4];
      a0 |= a.x > 0.f; a1 |= a.y > 0.f; a2 |= a.z > 0.f; a3 |= a.w > 0.f;
    }
    int m = m4 << 2;
    if (a0) s_reach[m] = 1;
    if (a1) s_reach[m + 1] = 1;
    if (a2) s_reach[m + 2] = 1;
    if (a3) s_reach[m + 3] = 1;
  }
  __syncthreads();

  // P2: fused sel1 argmax + sel2 top-2
  {
    bool c0 = s_avail[n0] && s_reach[n0];
    bool c1 = s_avail[n1] && s_reach[n1];
    for (int i = 0; i <= 3 * c; i++) {
      int w = s_win[i];
      c0 &= (n0 != w);
      c1 &= (n1 != w);
    }
    float bv = -FLT_MAX;
    int bi = NB;
    if (c0) { float y = s_logits[n0] + g1a; if (y > bv) { bv = y; bi = n0; } }
    if (c1) { float y = s_logits[n1] + g1b; if (y > bv || (y == bv && n1 < bi)) { bv = y; bi = n1; } }
    unsigned long long ka = c0 ? packKey(s_logits[n0] + g2a, n0) : 0ull;
    unsigned long long kb = c1 ? packKey(s_logits[n1] + g2b, n1) : 0ull;
    unsigned long long t1 = ka > kb ? ka : kb, t2 = ka > kb ? kb : ka;
#pragma unroll
    for (int off = 32; off; off >>= 1) {
      float ov = __shfl_down(bv, off);
      int oi = __shfl_down(bi, off);
      if (ov > bv || (ov == bv && oi < bi)) { bv = ov; bi = oi; }
      unsigned long long o1 = __shfl_down(t1, off);
      unsigned long long o2 = __shfl_down(t2, off);
      unsigned long long lo = t1 < o1 ? t1 : o1;
      unsigned long long hi2 = t2 > o2 ? t2 : o2;
      t1 = t1 > o1 ? t1 : o1;
      t2 = lo > hi2 ? lo : hi2;
    }
    if ((tid & 63) == 0) {
      if (bi < NB) atomicMax(&s_key1, packKey(bv, bi));
      s_top2[wid][0] = t1;
      s_top2[wid][1] = t2;
    }
  }
  __syncthreads();

  // P3: merge winners + gi + emb (redundant decode, no extra barrier)
  {
    int w1 = decodeKey(s_key1);
    unsigned long long t1 = 0ull, t2 = 0ull;
#pragma unroll
    for (int i = 0; i < 16; i++) {
      unsigned long long k = s_top2[i][0];
      if (k > t1) { t2 = t1; t1 = k; } else if (k > t2) t2 = k;
      k = s_top2[i][1];
      if (k > t1) { t2 = t1; t1 = k; } else if (k > t2) t2 = k;
    }
    int i1 = decodeKey(t1);
    int w2 = (i1 == w1) ? decodeKey(t2) : i1;
    int mc = (seed >= 0) + (w1 >= 0) + (w2 >= 0);
    float invmc = 1.0f / fmaxf((float)mc, 1.0f);

    if (tid < 768) {  // gi = bih + Wih @ emb  (4-lane split over 192 rows)
      int row = tid >> 2, g = tid & 3;
      const float4* wr = (const float4*)(Wih + (size_t)row * DD) + g * 8;
      const float4* x0 = (seed >= 0) ? (const float4*)(x + xb + (size_t)seed * DD) + g * 8 : nullptr;
      const float4* x1 = (w1 >= 0) ? (const float4*)(x + xb + (size_t)w1 * DD) + g * 8 : nullptr;
      const float4* x2 = (w2 >= 0) ? (const float4*)(x + xb + (size_t)w2 * DD) + g * 8 : nullptr;
      float s = 0.f;
#pragma unroll
      for (int i = 0; i < 8; i++) {
        float4 w = wr[i];
        float sx = 0.f, sy = 0.f, sz = 0.f, sw = 0.f;
        if (x0) { float4 v = x0[i]; sx += v.x; sy += v.y; sz += v.z; sw += v.w; }
        if (x1) { float4 v = x1[i]; sx += v.x; sy += v.y; sz += v.z; sw += v.w; }
        if (x2) { float4 v = x2[i]; sx += v.x; sy += v.y; sz += v.z; sw += v.w; }
        s += w.x * sx + w.y * sy + w.z * sz + w.w * sw;
      }
      s += __shfl_xor(s, 1);
      s += __shfl_xor(s, 2);
      if (g == 0) ws[OFF_GI + ((size_t)b * MAXC + c) * 3 * HH + row] = s * invmc + bih[row];
    } else if (tid < 768 + DD) {  // emb -> out_feat
      int d = tid - 768;
      float acc = 0.f;
      if (seed >= 0) acc += x[xb + (size_t)seed * DD + d];
      if (w1 >= 0) acc += x[xb + (size_t)w1 * DD + d];
      if (w2 >= 0) acc += x[xb + (size_t)w2 * DD + d];
      out_feat[((size_t)b * MAXC + c) * DD + d] = acc * invmc;
    } else if (tid == 896) winners[3 * c + 1] = w1;
    else if (tid == 897) winners[3 * c + 2] = w2;
  }
}

// ---------------- gru: GRU over history 0..c + q for next cluster ----------------
__global__ __launch_bounds__(256) void gvp_gru(
    const float* __restrict__ Whh, const float* __restrict__ bhh,
    const float* __restrict__ W1, const float* __restrict__ b1,
    float* __restrict__ ws, int c) {
  __shared__ __align__(16) float s_Whh[3 * HH][HH + 4];
  __shared__ __align__(16) float s_W1c[HH][HH + 4];
  __shared__ __align__(16) float s_gi[MAXC][3 * HH];
  __shared__ __align__(16) float s_h[2][HH];
  __shared__ float s_bhh[3 * HH];
  const int b = blockIdx.x, tid = threadIdx.x;

  for (int i = tid; i < 3 * HH * 16; i += 256) {
    int r = i >> 4, q = i & 15;
    *(float4*)&s_Whh[r][q * 4] = *(const float4*)(Whh + (size_t)r * HH + q * 4);
  }
  for (int i = tid; i < HH * 16; i += 256) {
    int r = i >> 4, q = i & 15;
    *(float4*)&s_W1c[r][q * 4] = *(const float4*)(W1 + (size_t)r * (DD + HH) + DD + q * 4);
  }
  if (tid < 3 * HH) {
    s_bhh[tid] = bhh[tid];
    for (int t = 0; t <= c; t++)
      s_gi[t][tid] = ws[OFF_GI + ((size_t)b * MAXC + t) * 3 * HH + tid];
  }
  if (tid < HH) s_h[0][tid] = ws[OFF_HRUN + b * HH + tid];
  __syncthreads();

  int hp = 0;
  for (int t = 0; t <= c; t++) {
    int row = tid >> 2, g = tid & 3;
    const float4* h4 = (const float4*)s_h[hp] + g * 4;
    float4 hv[4];
#pragma unroll
    for (int i = 0; i < 4; i++) hv[i] = h4[i];
    const float4* wr = (const float4*)&s_Whh[row][0] + g * 4;
    const float4* wz = (const float4*)&s_Whh[HH + row][0] + g * 4;
    const float4* wn = (const float4*)&s_Whh[2 * HH + row][0] + g * 4;
    float sr = 0.f, sz = 0.f, sn = 0.f;
#pragma unroll
    for (int i = 0; i < 4; i++) {
      float4 a = wr[i], bz = wz[i], cn = wn[i], h = hv[i];
      sr += a.x * h.x + a.y * h.y + a.z * h.z + a.w * h.w;
      sz += bz.x * h.x + bz.y * h.y + bz.z * h.z + bz.w * h.w;
      sn += cn.x * h.x + cn.y * h.y + cn.z * h.z + cn.w * h.w;
    }
    sr += __shfl_xor(sr, 1); sr += __shfl_xor(sr, 2);
    sz += __shfl_xor(sz, 1); sz += __shfl_xor(sz, 2);
    sn += __shfl_xor(sn, 1); sn += __shfl_xor(sn, 2);
    if (g == 0) {
      float r = 1.f / (1.f + expf(-(s_gi[t][row] + sr + s_bhh[row])));
      float z = 1.f / (1.f + expf(-(s_gi[t][HH + row] + sz + s_bhh[HH + row])));
      float nn = tanhf(s_gi[t][2 * HH + row] + r * (sn + s_bhh[2 * HH + row]));
      s_h[hp ^ 1][row] = (1.f - z) * nn + z * s_h[hp][row];
    }
    hp ^= 1;
    __syncthreads();
  }
  {  // q = b1 + W1c @ ctx  (ctx = s_h[hp])
    int row = tid >> 2, g = tid & 3;
    const float4* wr = (const float4*)&s_W1c[row][0] + g * 4;
    const float4* c4 = (const float4*)s_h[hp] + g * 4;
    float s = 0.f;
#pragma unroll
    for (int i = 0; i < 4; i++) {
      float4 w = wr[i], cc = c4[i];
      s += w.x * cc.x + w.y * cc.y + w.z * cc.z + w.w * cc.w;
    }
    s += __shfl_xor(s, 1);
    s += __shfl_xor(s, 2);
    if (g == 0) ws[OFF_QV + b * HH + row] = s + b1[row];
  }
  if (tid < HH) ws[OFF_HRUN + b * HH + tid] = s_h[hp][tid];
}

// ---------------- final: assign + cluster_adj writes ----------------
__global__ __launch_bounds__(NT) void gvp_final(
    const float* __restrict__ ws, float* __restrict__ out_adjm, float* __restrict__ out_assign) {
  __shared__ int s_win[16];
  const int tid = threadIdx.x;
  if (blockIdx.x < 160) {
    int b = blockIdx.x / 10;
    const int* winners = (const int*)(ws + OFF_WIN) + b * 16;
    if (tid < 16) s_win[tid] = (tid < 15) ? winners[tid] : -1;
    __syncthreads();
    int r = (blockIdx.x % 10) * NT + tid;  // < 10240
    int n = r / 5, cc = r - 5 * n;
    int m0 = s_win[3 * cc], m1 = s_win[3 * cc + 1], m2 = s_win[3 * cc + 2];
    out_assign[(size_t)b * (NB * MAXC) + r] = (n == m0 || n == m1 || n == m2) ? 1.0f : 0.0f;
  } else {
    if (tid < BB * MAXC * MAXC) {
      int i = tid % (MAXC * MAXC);
      out_adjm[tid] = ((i / MAXC) == (i % MAXC)) ? 0.f : 1.f;
    }
  }
}

extern "C" void kernel_launch(void* const* d_in, const int* in_sizes, int n_in,
                              void* d_out, int out_size, void* d_ws, size_t ws_size,
                              hipStream_t stream) {
  const float* x   = (const float*)d_in[0];
  const float* adj = (const float*)d_in[1];
  const int*   mask= (const int*)d_in[2];
  const float* W1  = (const float*)d_in[3];
  const float* b1  = (const float*)d_in[4];
  const float* W2  = (const float*)d_in[5];
  const float* b2  = (const float*)d_in[6];
  const float* Wc  = (const float*)d_in[7];
  const float* bc  = (const float*)d_in[8];
  const float* Wih = (const float*)d_in[9];
  const float* Whh = (const float*)d_in[10];
  const float* bih = (const float*)d_in[11];
  const float* bhh = (const float*)d_in[12];

  float* ws = (float*)d_ws;
  float* out = (float*)d_out;
  float* out_feat = out;                                     // [B,5,D]
  float* out_adjm = out + (size_t)BB * MAXC * DD;            // [B,5,5]
  float* out_assign = out_adjm + (size_t)BB * MAXC * MAXC;   // [B,N,5]

  hipLaunchKernelGGL(gvp_prep, dim3(384), dim3(NT), 0, stream, x, W1, ws);
  hipLaunchKernelGGL(gvp_init, dim3(BB), dim3(256), 0, stream, Wc, bc, W1, b1, ws);
  for (int c = 0; c < MAXC; c++) {
    hipLaunchKernelGGL(gvp_selA, dim3(BB), dim3(NT), 0, stream, mask, W2, b2, ws, c);
    hipLaunchKernelGGL(gvp_selB, dim3(BB), dim3(NT), 0, stream,
                       x, adj, mask, Wih, bih, ws, out_feat, c);
    if (c + 1 < MAXC)
      hipLaunchKernelGGL(gvp_gru, dim3(BB), dim3(256), 0, stream, Whh, bhh, W1, b1, ws, c);
  }
  hipLaunchKernelGGL(gvp_final, dim3(161), dim3(NT), 0, stream, ws, out_adjm, out_assign);
}